// Round 1
// baseline (366.602 us; speedup 1.0000x reference)
//
#include <hip/hip_runtime.h>
#include <hip/hip_bf16.h>

typedef __attribute__((ext_vector_type(4))) float f32x4;
typedef __attribute__((ext_vector_type(8))) short bf16x8;

#define BA 48
#define BB 48
#define SS 96
#define DIN 768
#define HH 256

static __device__ __forceinline__ short f2bf(float f) {
    __hip_bfloat16 h = __float2bfloat16(f);
    return *reinterpret_cast<short*>(&h);
}

static __device__ __forceinline__ f32x4 mfma16(bf16x8 a, bf16x8 b, f32x4 c) {
    return __builtin_amdgcn_mfma_f32_16x16x32_bf16(a, b, c, 0, 0, 0);
}

// ---------------------------------------------------------------------------
// Kernel 0: convert+transpose weights: W[768][256] f32 -> Wt[3][256][768] bf16
// ---------------------------------------------------------------------------
__global__ void wt_kernel(const float* __restrict__ Wq, const float* __restrict__ Wk,
                          const float* __restrict__ Wv, short* __restrict__ wt) {
    int idx = blockIdx.x * 256 + threadIdx.x;
    if (idx >= 3 * DIN * HH) return;
    int mat = idx / (DIN * HH);
    int rem = idx - mat * DIN * HH;
    int k = rem / HH;
    int n = rem - k * HH;
    const float* W = (mat == 0) ? Wq : (mat == 1) ? Wk : Wv;
    wt[(mat * HH + n) * DIN + k] = f2bf(W[k * HH + n]);
}

// ---------------------------------------------------------------------------
// Kernel 1: QKV projection. grid (48, 3): blockIdx.x = batch, y = mat(0=q,1=k,2=v)
// 384 threads = 6 waves; wave w computes rows 16w..16w+15 x all 256 cols.
// q: store q f32 + qn bf16 (L2-row-normalized); k: kn bf16; v: vt bf16 transposed [H][S].
// ---------------------------------------------------------------------------
__global__ __launch_bounds__(384) void qkv_kernel(
    const float* __restrict__ Xa, const float* __restrict__ Xb,
    const float* __restrict__ bq, const float* __restrict__ bk, const float* __restrict__ bv,
    const short* __restrict__ wt,
    float* __restrict__ q_ws, short* __restrict__ qn_ws,
    short* __restrict__ kn_ws, short* __restrict__ vt_ws) {
    __shared__ short vtile[SS][HH + 8];

    int bb = blockIdx.x;
    int mat = blockIdx.y;
    int tid = threadIdx.x;
    int wave = tid >> 6, lane = tid & 63;
    int c = lane & 15, g = lane >> 4;

    const float* X = ((mat == 0) ? Xa : Xb) + bb * SS * DIN;
    const short* Wt = wt + mat * HH * DIN;
    const float* bias = (mat == 0) ? bq : (mat == 1) ? bk : bv;

    const f32x4 z4 = {0.f, 0.f, 0.f, 0.f};
    f32x4 acc[16];
#pragma unroll
    for (int n = 0; n < 16; ++n) acc[n] = z4;

    const float* ap = X + (16 * wave + c) * DIN + g * 8;
    const short* bp = Wt + c * DIN + g * 8;
    for (int kk = 0; kk < DIN; kk += 32) {
        f32x4 a0 = *reinterpret_cast<const f32x4*>(ap + kk);
        f32x4 a1 = *reinterpret_cast<const f32x4*>(ap + kk + 4);
        bf16x8 af;
        af[0] = f2bf(a0[0]); af[1] = f2bf(a0[1]); af[2] = f2bf(a0[2]); af[3] = f2bf(a0[3]);
        af[4] = f2bf(a1[0]); af[5] = f2bf(a1[1]); af[6] = f2bf(a1[2]); af[7] = f2bf(a1[3]);
#pragma unroll
        for (int n = 0; n < 16; ++n) {
            bf16x8 bf = *reinterpret_cast<const bf16x8*>(bp + n * 16 * DIN + kk);
            acc[n] = mfma16(af, bf, acc[n]);
        }
    }
    // bias
#pragma unroll
    for (int n = 0; n < 16; ++n) {
        float bv_ = bias[n * 16 + c];
#pragma unroll
        for (int r = 0; r < 4; ++r) acc[n][r] += bv_;
    }

    if (mat < 2) {
        // row L2 norms: rows = 16*wave + 4g + r, cols spread over 16 lanes x 16 frags
        float s2[4] = {0.f, 0.f, 0.f, 0.f};
#pragma unroll
        for (int n = 0; n < 16; ++n)
#pragma unroll
            for (int r = 0; r < 4; ++r) s2[r] += acc[n][r] * acc[n][r];
#pragma unroll
        for (int m = 1; m < 16; m <<= 1)
#pragma unroll
            for (int r = 0; r < 4; ++r) s2[r] += __shfl_xor(s2[r], m);
        float inv[4];
#pragma unroll
        for (int r = 0; r < 4; ++r) inv[r] = 1.0f / fmaxf(sqrtf(s2[r]), 1e-8f);

        short* qn = (mat == 0) ? qn_ws : kn_ws;
#pragma unroll
        for (int n = 0; n < 16; ++n) {
#pragma unroll
            for (int r = 0; r < 4; ++r) {
                int row = bb * SS + 16 * wave + 4 * g + r;
                int col = n * 16 + c;
                if (mat == 0) q_ws[row * HH + col] = acc[n][r];
                qn[row * HH + col] = f2bf(acc[n][r] * inv[r]);
            }
        }
    } else {
        // v: transpose via LDS -> vt[b][d][j] bf16
#pragma unroll
        for (int n = 0; n < 16; ++n)
#pragma unroll
            for (int r = 0; r < 4; ++r)
                vtile[16 * wave + 4 * g + r][n * 16 + c] = f2bf(acc[n][r]);
        __syncthreads();
        if (tid < HH) {
            int d = tid;
#pragma unroll
            for (int ch = 0; ch < 12; ++ch) {
                bf16x8 pack;
#pragma unroll
                for (int j = 0; j < 8; ++j) pack[j] = vtile[ch * 8 + j][d];
                *reinterpret_cast<bf16x8*>(vt_ws + (bb * HH + d) * SS + ch * 8) = pack;
            }
        }
    }
}

// ---------------------------------------------------------------------------
// Kernel 2: per (a,b) pair: C = qn_a kn_b^T -> exp -> Sinkhorn (scaling vectors)
// -> row-L2-normalize -> T @ v_b + q_a -> LayerNorm -> out.
// grid (48 b, 48 a), 384 threads = 6 waves.
// ---------------------------------------------------------------------------
__global__ __launch_bounds__(384) void attn_kernel(
    const short* __restrict__ qn_ws, const short* __restrict__ kn_ws,
    const float* __restrict__ q_ws, const short* __restrict__ vt_ws,
    const float* __restrict__ ln_g, const float* __restrict__ ln_b,
    float* __restrict__ out) {
    __shared__ float Kt[SS][SS + 1];   // exp(C/eps), padded
    __shared__ float vv[SS];
    __shared__ float uu[SS];
    __shared__ float rn[SS];
    __shared__ float part[4 * SS];

    int b = blockIdx.x, a = blockIdx.y;
    int tid = threadIdx.x;
    int wave = tid >> 6, lane = tid & 63;
    int c = lane & 15, g = lane >> 4;

    const short* qn_a = qn_ws + a * SS * HH;
    const short* kn_b = kn_ws + b * SS * HH;

    // ---- Phase A: C = qn kn^T via MFMA; exp into LDS ----
    const f32x4 z4 = {0.f, 0.f, 0.f, 0.f};
    f32x4 cacc[6];
#pragma unroll
    for (int n = 0; n < 6; ++n) cacc[n] = z4;

    const short* ap = qn_a + (16 * wave + c) * HH + g * 8;
    const short* bp = kn_b + c * HH + g * 8;
#pragma unroll
    for (int kk = 0; kk < HH; kk += 32) {
        bf16x8 af = *reinterpret_cast<const bf16x8*>(ap + kk);
#pragma unroll
        for (int n = 0; n < 6; ++n) {
            bf16x8 bf = *reinterpret_cast<const bf16x8*>(bp + n * 16 * HH + kk);
            cacc[n] = mfma16(af, bf, cacc[n]);
        }
    }
    if (tid < SS) vv[tid] = 1.0f;
#pragma unroll
    for (int n = 0; n < 6; ++n)
#pragma unroll
        for (int r = 0; r < 4; ++r)
            Kt[16 * wave + 4 * g + r][n * 16 + c] =
                exp2f(cacc[n][r] * 14.4269504088896341f);  // exp(10*C)
    __syncthreads();

    // ---- Phase B: Sinkhorn scaling vectors: u = 1/(K vv); vv = 1/(K^T u) ----
    int rr = tid >> 2, s4 = tid & 3;
    int j0 = s4 * 24;
    for (int it = 0; it < 5; ++it) {
        float sum = 0.f;
#pragma unroll
        for (int jj = 0; jj < 24; ++jj) sum += Kt[rr][j0 + jj] * vv[j0 + jj];
        part[tid] = sum;
        __syncthreads();
        if (tid < SS)
            uu[tid] = 1.0f / (part[4 * tid] + part[4 * tid + 1] + part[4 * tid + 2] + part[4 * tid + 3]);
        __syncthreads();
        sum = 0.f;
#pragma unroll
        for (int ii = 0; ii < 24; ++ii) sum += Kt[j0 + ii][rr] * uu[j0 + ii];
        part[tid] = sum;
        __syncthreads();
        if (tid < SS)
            vv[tid] = 1.0f / (part[4 * tid] + part[4 * tid + 1] + part[4 * tid + 2] + part[4 * tid + 3]);
        __syncthreads();
    }

    // ---- Phase C: row L2 norm of K*diag(vv)  (u cancels in normalization) ----
    {
        float sum = 0.f;
#pragma unroll
        for (int jj = 0; jj < 24; ++jj) {
            float p = Kt[rr][j0 + jj] * vv[j0 + jj];
            sum += p * p;
        }
        part[tid] = sum;
        __syncthreads();
        if (tid < SS) {
            float s = part[4 * tid] + part[4 * tid + 1] + part[4 * tid + 2] + part[4 * tid + 3];
            rn[tid] = 1.0f / fmaxf(sqrtf(s), 1e-12f);
        }
        __syncthreads();
    }

    // ---- Phase D: build T fragments (bf16) in registers ----
    bf16x8 afr[3];
    {
        int i = 16 * wave + c;
        float invn = rn[i];
#pragma unroll
        for (int ks = 0; ks < 3; ++ks) {
#pragma unroll
            for (int j = 0; j < 8; ++j) {
                int jj = ks * 32 + g * 8 + j;
                afr[ks][j] = f2bf(Kt[i][jj] * vv[jj] * invn);
            }
        }
    }

    // ---- Phase E: attended = T @ v  (B-frags from transposed v) ----
    f32x4 acc[16];
#pragma unroll
    for (int n = 0; n < 16; ++n) acc[n] = z4;
    const short* vp = vt_ws + (b * HH + c) * SS + g * 8;
#pragma unroll
    for (int ks = 0; ks < 3; ++ks)
#pragma unroll
        for (int n = 0; n < 16; ++n) {
            bf16x8 bf = *reinterpret_cast<const bf16x8*>(vp + n * 16 * SS + ks * 32);
            acc[n] = mfma16(afr[ks], bf, acc[n]);
        }

    // ---- Phase F: + q residual, LayerNorm, store ----
    const float* qa = q_ws + a * SS * HH;
    int r0 = 16 * wave + 4 * g;
    float s1[4] = {0.f, 0.f, 0.f, 0.f};
    float s2[4] = {0.f, 0.f, 0.f, 0.f};
#pragma unroll
    for (int n = 0; n < 16; ++n)
#pragma unroll
        for (int r = 0; r < 4; ++r) {
            float x = acc[n][r] + qa[(r0 + r) * HH + n * 16 + c];
            acc[n][r] = x;
            s1[r] += x;
            s2[r] += x * x;
        }
#pragma unroll
    for (int m = 1; m < 16; m <<= 1)
#pragma unroll
        for (int r = 0; r < 4; ++r) {
            s1[r] += __shfl_xor(s1[r], m);
            s2[r] += __shfl_xor(s2[r], m);
        }
    float mean[4], inv[4];
#pragma unroll
    for (int r = 0; r < 4; ++r) {
        mean[r] = s1[r] * (1.0f / 256.0f);
        float var = s2[r] * (1.0f / 256.0f) - mean[r] * mean[r];
        inv[r] = rsqrtf(var + 1e-5f);
    }
    float* ob = out + ((size_t)(a * BB + b)) * SS * HH;
#pragma unroll
    for (int n = 0; n < 16; ++n) {
        float gg = ln_g[n * 16 + c];
        float bb_ = ln_b[n * 16 + c];
#pragma unroll
        for (int r = 0; r < 4; ++r)
            ob[(r0 + r) * HH + n * 16 + c] = (acc[n][r] - mean[r]) * inv[r] * gg + bb_;
    }
}

// ---------------------------------------------------------------------------
extern "C" void kernel_launch(void* const* d_in, const int* in_sizes, int n_in,
                              void* d_out, int out_size, void* d_ws, size_t ws_size,
                              hipStream_t stream) {
    const float* Xa = (const float*)d_in[0];
    const float* Xb = (const float*)d_in[1];
    const float* Wq = (const float*)d_in[2];
    const float* bq = (const float*)d_in[3];
    const float* Wk = (const float*)d_in[4];
    const float* bk = (const float*)d_in[5];
    const float* Wv = (const float*)d_in[6];
    const float* bv = (const float*)d_in[7];
    const float* ln_g = (const float*)d_in[8];
    const float* ln_b = (const float*)d_in[9];
    float* out = (float*)d_out;

    char* ws = (char*)d_ws;
    short* wt    = (short*)(ws);              // 3*256*768*2 = 1,179,648 B
    float* q_ws  = (float*)(ws + 1179648);    // 4608*256*4  = 4,718,592 B
    short* qn_ws = (short*)(ws + 5898240);    // 4608*256*2  = 2,359,296 B
    short* kn_ws = (short*)(ws + 8257536);    // 4608*256*2  = 2,359,296 B
    short* vt_ws = (short*)(ws + 10616832);   // 48*256*96*2 = 2,359,296 B  (end 12,976,128)

    wt_kernel<<<dim3((3 * DIN * HH + 255) / 256), dim3(256), 0, stream>>>(Wq, Wk, Wv, wt);
    qkv_kernel<<<dim3(BA, 3), dim3(384), 0, stream>>>(Xa, Xb, bq, bk, bv, wt,
                                                      q_ws, qn_ws, kn_ws, vt_ws);
    attn_kernel<<<dim3(BB, BA), dim3(384), 0, stream>>>(qn_ws, kn_ws, q_ws, vt_ws,
                                                        ln_g, ln_b, out);
}

// Round 2
// 359.270 us; speedup vs baseline: 1.0204x; 1.0204x over previous
//
#include <hip/hip_runtime.h>
#include <hip/hip_bf16.h>

typedef __attribute__((ext_vector_type(4))) float f32x4;
typedef __attribute__((ext_vector_type(8))) short bf16x8;
typedef __attribute__((ext_vector_type(4))) short s16x4;

#define BA 48
#define BB 48
#define SS 96
#define DIN 768
#define HH 256

static __device__ __forceinline__ short f2bf(float f) {
    __hip_bfloat16 h = __float2bfloat16(f);
    return *reinterpret_cast<short*>(&h);
}

static __device__ __forceinline__ f32x4 mfma16(bf16x8 a, bf16x8 b, f32x4 c) {
    return __builtin_amdgcn_mfma_f32_16x16x32_bf16(a, b, c, 0, 0, 0);
}

// ---------------------------------------------------------------------------
// Kernel 0: convert+transpose weights: W[768][256] f32 -> Wt[3][256][768] bf16
// ---------------------------------------------------------------------------
__global__ void wt_kernel(const float* __restrict__ Wq, const float* __restrict__ Wk,
                          const float* __restrict__ Wv, short* __restrict__ wt) {
    int idx = blockIdx.x * 256 + threadIdx.x;
    if (idx >= 3 * DIN * HH) return;
    int mat = idx / (DIN * HH);
    int rem = idx - mat * DIN * HH;
    int k = rem / HH;
    int n = rem - k * HH;
    const float* W = (mat == 0) ? Wq : (mat == 1) ? Wk : Wv;
    wt[(mat * HH + n) * DIN + k] = f2bf(W[k * HH + n]);
}

// ---------------------------------------------------------------------------
// Kernel 1: QKV projection, split 4x along N for occupancy.
// grid (48, 3, 4): batch, mat(0=q,1=k,2=v), 64-col tile. 384 thr = 6 waves.
// Wave w: rows 16w..16w+15 x 64 cols. q,k -> f32 (norms done later); v -> vt bf16 [H][S].
// ---------------------------------------------------------------------------
__global__ __launch_bounds__(384) void qkv_kernel(
    const float* __restrict__ Xa, const float* __restrict__ Xb,
    const float* __restrict__ bq, const float* __restrict__ bk, const float* __restrict__ bv,
    const short* __restrict__ wt,
    float* __restrict__ q_ws, float* __restrict__ k_ws, short* __restrict__ vt_ws) {
    __shared__ short vtile[64][104];

    int bb = blockIdx.x;
    int mat = blockIdx.y;
    int c0 = blockIdx.z * 64;
    int tid = threadIdx.x;
    int wave = tid >> 6, lane = tid & 63;
    int c = lane & 15, g = lane >> 4;

    const float* X = ((mat == 0) ? Xa : Xb) + bb * SS * DIN;
    const short* Wt = wt + mat * HH * DIN;
    const float* bias = (mat == 0) ? bq : (mat == 1) ? bk : bv;

    const f32x4 z4 = {0.f, 0.f, 0.f, 0.f};
    f32x4 acc[4];
#pragma unroll
    for (int n = 0; n < 4; ++n) acc[n] = z4;

    const float* ap = X + (16 * wave + c) * DIN + g * 8;
    const short* bp = Wt + (c0 + c) * DIN + g * 8;
    for (int kk = 0; kk < DIN; kk += 32) {
        f32x4 a0 = *reinterpret_cast<const f32x4*>(ap + kk);
        f32x4 a1 = *reinterpret_cast<const f32x4*>(ap + kk + 4);
        bf16x8 af;
        af[0] = f2bf(a0[0]); af[1] = f2bf(a0[1]); af[2] = f2bf(a0[2]); af[3] = f2bf(a0[3]);
        af[4] = f2bf(a1[0]); af[5] = f2bf(a1[1]); af[6] = f2bf(a1[2]); af[7] = f2bf(a1[3]);
#pragma unroll
        for (int n = 0; n < 4; ++n) {
            bf16x8 bf = *reinterpret_cast<const bf16x8*>(bp + n * 16 * DIN + kk);
            acc[n] = mfma16(af, bf, acc[n]);
        }
    }
#pragma unroll
    for (int n = 0; n < 4; ++n) {
        float bv_ = bias[c0 + n * 16 + c];
#pragma unroll
        for (int r = 0; r < 4; ++r) acc[n][r] += bv_;
    }

    if (mat < 2) {
        float* dst = (mat == 0) ? q_ws : k_ws;
#pragma unroll
        for (int n = 0; n < 4; ++n)
#pragma unroll
            for (int r = 0; r < 4; ++r)
                dst[(bb * SS + 16 * wave + 4 * g + r) * HH + c0 + n * 16 + c] = acc[n][r];
    } else {
#pragma unroll
        for (int n = 0; n < 4; ++n)
#pragma unroll
            for (int r = 0; r < 4; ++r)
                vtile[n * 16 + c][16 * wave + 4 * g + r] = f2bf(acc[n][r]);
        __syncthreads();
#pragma unroll
        for (int t2 = 0; t2 < 2; ++t2) {
            int t = tid + t2 * 384;
            int d = t / 12, ch = t % 12;
            bf16x8 pk = *reinterpret_cast<const bf16x8*>(&vtile[d][ch * 8]);
            *reinterpret_cast<bf16x8*>(vt_ws + ((size_t)(bb * HH) + c0 + d) * SS + ch * 8) = pk;
        }
    }
}

// ---------------------------------------------------------------------------
// Kernel 2: row L2 norms for q,k -> qn,kn bf16. One wave per row.
// grid 2304 blocks x 256 thr (4 waves); rows 0..4607 = q, 4608..9215 = k.
// ---------------------------------------------------------------------------
__global__ __launch_bounds__(256) void norm_kernel(
    const float* __restrict__ q_ws, const float* __restrict__ k_ws,
    short* __restrict__ qn_ws, short* __restrict__ kn_ws) {
    int row = blockIdx.x * 4 + (threadIdx.x >> 6);
    int lane = threadIdx.x & 63;
    int isq = (row < 4608);
    const float* src = isq ? q_ws : k_ws;
    short* dst = isq ? qn_ws : kn_ws;
    int r = isq ? row : row - 4608;

    f32x4 v = *reinterpret_cast<const f32x4*>(src + (size_t)r * HH + lane * 4);
    float s = v[0] * v[0] + v[1] * v[1] + v[2] * v[2] + v[3] * v[3];
#pragma unroll
    for (int m = 1; m < 64; m <<= 1) s += __shfl_xor(s, m);
    float inv = 1.0f / fmaxf(sqrtf(s), 1e-8f);
    s16x4 o;
#pragma unroll
    for (int j = 0; j < 4; ++j) o[j] = f2bf(v[j] * inv);
    *reinterpret_cast<s16x4*>(dst + (size_t)r * HH + lane * 4) = o;
}

// ---------------------------------------------------------------------------
// Kernel 3: fused attn per (a,b) pair. Register-resident Sinkhorn.
// Swapped QK^T (mfma(kn,qn)) -> lane owns C[i=16w+c][j=16f+4g+r], 24 f32.
// Row norm: local sum + shfl_xor(16,32). Col norm: shfl_xor(1,2,4,8) + 2.3KB LDS.
// T -> 20KB LDS bf16 -> PV MFMA -> +q residual -> LayerNorm -> out.
// grid (48 b, 48 a), 384 thr = 6 waves; LDS 22.6KB; VGPR capped at 102.
// ---------------------------------------------------------------------------
__global__ __launch_bounds__(384, 5) void attn_kernel(
    const short* __restrict__ qn_ws, const short* __restrict__ kn_ws,
    const float* __restrict__ q_ws, const short* __restrict__ vt_ws,
    const float* __restrict__ ln_g, const float* __restrict__ ln_b,
    float* __restrict__ out) {
    __shared__ short Tl[SS][104];        // 19968 B, bf16 T
    __shared__ float colpart[6][SS];     // 2304 B
    __shared__ float cinv[SS];           // 384 B

    int b = blockIdx.x, a = blockIdx.y;
    int tid = threadIdx.x;
    int wave = tid >> 6, lane = tid & 63;
    int c = lane & 15, g = lane >> 4;

    // ---- QK^T (swapped): K[f][r] = C[i][j], i = 16*wave + c, j = 16f + 4g + r ----
    const f32x4 z4 = {0.f, 0.f, 0.f, 0.f};
    f32x4 K[6];
#pragma unroll
    for (int f = 0; f < 6; ++f) K[f] = z4;

    const short* qp = qn_ws + ((size_t)(a * SS) + 16 * wave + c) * HH + g * 8;  // B operand
    const short* kp = kn_ws + ((size_t)(b * SS) + c) * HH + g * 8;              // A operand
#pragma unroll
    for (int kk = 0; kk < HH; kk += 32) {
        bf16x8 qf = *reinterpret_cast<const bf16x8*>(qp + kk);
#pragma unroll
        for (int f = 0; f < 6; ++f) {
            bf16x8 kf = *reinterpret_cast<const bf16x8*>(kp + f * 16 * HH + kk);
            K[f] = mfma16(kf, qf, K[f]);
        }
    }

    // ---- exp(C/eps) = exp2(C * 10*log2(e)) ----
#pragma unroll
    for (int f = 0; f < 6; ++f)
#pragma unroll
        for (int r = 0; r < 4; ++r)
            K[f][r] = exp2f(K[f][r] * 14.4269504088896341f);

    // ---- Sinkhorn: 5 x (row normalize, col normalize), all in registers ----
    for (int it = 0; it < 5; ++it) {
        // row: sum over j (local 24 + across g via xor 16,32)
        float rs = 0.f;
#pragma unroll
        for (int f = 0; f < 6; ++f) rs += K[f][0] + K[f][1] + K[f][2] + K[f][3];
        rs += __shfl_xor(rs, 16);
        rs += __shfl_xor(rs, 32);
        float rinv = 1.0f / rs;
#pragma unroll
        for (int f = 0; f < 6; ++f)
#pragma unroll
            for (int r = 0; r < 4; ++r) K[f][r] *= rinv;

        // col: sum over i. In-wave: xor 1,2,4,8 over c. Cross-wave: LDS.
        f32x4 cs[6];
#pragma unroll
        for (int f = 0; f < 6; ++f) cs[f] = K[f];
#pragma unroll
        for (int m = 1; m < 16; m <<= 1)
#pragma unroll
            for (int f = 0; f < 6; ++f)
#pragma unroll
                for (int r = 0; r < 4; ++r) cs[f][r] += __shfl_xor(cs[f][r], m);
        if (c == 0) {
#pragma unroll
            for (int f = 0; f < 6; ++f)
                *reinterpret_cast<f32x4*>(&colpart[wave][16 * f + 4 * g]) = cs[f];
        }
        __syncthreads();
        if (tid < SS) {
            float s = colpart[0][tid] + colpart[1][tid] + colpart[2][tid] +
                      colpart[3][tid] + colpart[4][tid] + colpart[5][tid];
            cinv[tid] = 1.0f / s;
        }
        __syncthreads();
#pragma unroll
        for (int f = 0; f < 6; ++f) {
            f32x4 ci = *reinterpret_cast<const f32x4*>(&cinv[16 * f + 4 * g]);
#pragma unroll
            for (int r = 0; r < 4; ++r) K[f][r] *= ci[r];
        }
    }

    // ---- final row L2 normalize ----
    {
        float ss = 0.f;
#pragma unroll
        for (int f = 0; f < 6; ++f)
#pragma unroll
            for (int r = 0; r < 4; ++r) ss += K[f][r] * K[f][r];
        ss += __shfl_xor(ss, 16);
        ss += __shfl_xor(ss, 32);
        float linv = 1.0f / fmaxf(sqrtf(ss), 1e-12f);
#pragma unroll
        for (int f = 0; f < 6; ++f)
#pragma unroll
            for (int r = 0; r < 4; ++r) K[f][r] *= linv;
    }

    // ---- T (bf16) -> LDS: row i = 16w+c, cols 16f+4g+0..3 ----
#pragma unroll
    for (int f = 0; f < 6; ++f) {
        s16x4 pk;
#pragma unroll
        for (int r = 0; r < 4; ++r) pk[r] = f2bf(K[f][r]);
        *reinterpret_cast<s16x4*>(&Tl[16 * wave + c][16 * f + 4 * g]) = pk;
    }
    __syncthreads();

    // ---- PV: wave w -> i-tile w (i = 16w+4g+r), n = d-tiles 0..15 ----
    f32x4 acc[16];
#pragma unroll
    for (int n = 0; n < 16; ++n) acc[n] = z4;
    const short* vp = vt_ws + ((size_t)(b * HH) + c) * SS + g * 8;
#pragma unroll
    for (int ks = 0; ks < 3; ++ks) {
        bf16x8 af = *reinterpret_cast<const bf16x8*>(&Tl[16 * wave + c][ks * 32 + g * 8]);
#pragma unroll
        for (int n = 0; n < 16; ++n) {
            bf16x8 bf = *reinterpret_cast<const bf16x8*>(vp + n * 16 * SS + ks * 32);
            acc[n] = mfma16(af, bf, acc[n]);
        }
    }

    // ---- + q residual, LayerNorm, store ----
    const float* qa = q_ws + (size_t)a * SS * HH;
    int r0 = 16 * wave + 4 * g;
    float s1[4] = {0.f, 0.f, 0.f, 0.f};
    float s2[4] = {0.f, 0.f, 0.f, 0.f};
#pragma unroll
    for (int n = 0; n < 16; ++n)
#pragma unroll
        for (int r = 0; r < 4; ++r) {
            float x = acc[n][r] + qa[(r0 + r) * HH + n * 16 + c];
            acc[n][r] = x;
            s1[r] += x;
            s2[r] += x * x;
        }
#pragma unroll
    for (int m = 1; m < 16; m <<= 1)
#pragma unroll
        for (int r = 0; r < 4; ++r) {
            s1[r] += __shfl_xor(s1[r], m);
            s2[r] += __shfl_xor(s2[r], m);
        }
    float mean[4], inv[4];
#pragma unroll
    for (int r = 0; r < 4; ++r) {
        mean[r] = s1[r] * (1.0f / 256.0f);
        float var = s2[r] * (1.0f / 256.0f) - mean[r] * mean[r];
        inv[r] = rsqrtf(var + 1e-5f);
    }
    float* ob = out + ((size_t)(a * BB + b)) * SS * HH;
#pragma unroll
    for (int n = 0; n < 16; ++n) {
        float gg = ln_g[n * 16 + c];
        float bb_ = ln_b[n * 16 + c];
#pragma unroll
        for (int r = 0; r < 4; ++r)
            ob[(r0 + r) * HH + n * 16 + c] = (acc[n][r] - mean[r]) * inv[r] * gg + bb_;
    }
}

// ---------------------------------------------------------------------------
extern "C" void kernel_launch(void* const* d_in, const int* in_sizes, int n_in,
                              void* d_out, int out_size, void* d_ws, size_t ws_size,
                              hipStream_t stream) {
    const float* Xa = (const float*)d_in[0];
    const float* Xb = (const float*)d_in[1];
    const float* Wq = (const float*)d_in[2];
    const float* bq = (const float*)d_in[3];
    const float* Wk = (const float*)d_in[4];
    const float* bk = (const float*)d_in[5];
    const float* Wv = (const float*)d_in[6];
    const float* bv = (const float*)d_in[7];
    const float* ln_g = (const float*)d_in[8];
    const float* ln_b = (const float*)d_in[9];
    float* out = (float*)d_out;

    char* ws = (char*)d_ws;
    short* wt    = (short*)(ws);               // 1,179,648 B
    float* q_ws  = (float*)(ws + 1179648);     // 4,718,592 B
    float* k_ws  = (float*)(ws + 5898240);     // 4,718,592 B
    short* qn_ws = (short*)(ws + 10616832);    // 2,359,296 B
    short* kn_ws = (short*)(ws + 12976128);    // 2,359,296 B
    short* vt_ws = (short*)(ws + 15335424);    // 2,359,296 B (end 17,694,720)

    wt_kernel<<<dim3(2304), dim3(256), 0, stream>>>(Wq, Wk, Wv, wt);
    qkv_kernel<<<dim3(BA, 3, 4), dim3(384), 0, stream>>>(Xa, Xb, bq, bk, bv, wt,
                                                         q_ws, k_ws, vt_ws);
    norm_kernel<<<dim3(2304), dim3(256), 0, stream>>>(q_ws, k_ws, qn_ws, kn_ws);
    attn_kernel<<<dim3(BB, BA), dim3(384), 0, stream>>>(qn_ws, kn_ws, q_ws, vt_ws,
                                                        ln_g, ln_b, out);
}

// Round 3
// 353.657 us; speedup vs baseline: 1.0366x; 1.0159x over previous
//
#include <hip/hip_runtime.h>
#include <hip/hip_bf16.h>

typedef __attribute__((ext_vector_type(4))) float f32x4;
typedef __attribute__((ext_vector_type(8))) short bf16x8;
typedef __attribute__((ext_vector_type(4))) short s16x4;

#define BA 48
#define BB 48
#define SS 96
#define DIN 768
#define HH 256

static __device__ __forceinline__ short f2bf(float f) {
    __hip_bfloat16 h = __float2bfloat16(f);
    return *reinterpret_cast<short*>(&h);
}

static __device__ __forceinline__ f32x4 mfma16(bf16x8 a, bf16x8 b, f32x4 c) {
    return __builtin_amdgcn_mfma_f32_16x16x32_bf16(a, b, c, 0, 0, 0);
}

// ---------------------------------------------------------------------------
// Kernel 0: convert+transpose weights: W[768][256] f32 -> Wt[3][256][768] bf16
// ---------------------------------------------------------------------------
__global__ void wt_kernel(const float* __restrict__ Wq, const float* __restrict__ Wk,
                          const float* __restrict__ Wv, short* __restrict__ wt) {
    int idx = blockIdx.x * 256 + threadIdx.x;
    if (idx >= 3 * DIN * HH) return;
    int mat = idx / (DIN * HH);
    int rem = idx - mat * DIN * HH;
    int k = rem / HH;
    int n = rem - k * HH;
    const float* W = (mat == 0) ? Wq : (mat == 1) ? Wk : Wv;
    wt[(mat * HH + n) * DIN + k] = f2bf(W[k * HH + n]);
}

// ---------------------------------------------------------------------------
// Kernel 1: QKV projection, split 4x along N for occupancy.
// grid (48, 3, 4): batch, mat(0=q,1=k,2=v), 64-col tile. 384 thr = 6 waves.
// ---------------------------------------------------------------------------
__global__ __launch_bounds__(384) void qkv_kernel(
    const float* __restrict__ Xa, const float* __restrict__ Xb,
    const float* __restrict__ bq, const float* __restrict__ bk, const float* __restrict__ bv,
    const short* __restrict__ wt,
    float* __restrict__ q_ws, float* __restrict__ k_ws, short* __restrict__ vt_ws) {
    __shared__ short vtile[64][104];

    int bb = blockIdx.x;
    int mat = blockIdx.y;
    int c0 = blockIdx.z * 64;
    int tid = threadIdx.x;
    int wave = tid >> 6, lane = tid & 63;
    int c = lane & 15, g = lane >> 4;

    const float* X = ((mat == 0) ? Xa : Xb) + bb * SS * DIN;
    const short* Wt = wt + mat * HH * DIN;
    const float* bias = (mat == 0) ? bq : (mat == 1) ? bk : bv;

    const f32x4 z4 = {0.f, 0.f, 0.f, 0.f};
    f32x4 acc[4];
#pragma unroll
    for (int n = 0; n < 4; ++n) acc[n] = z4;

    const float* ap = X + (16 * wave + c) * DIN + g * 8;
    const short* bp = Wt + (c0 + c) * DIN + g * 8;
    for (int kk = 0; kk < DIN; kk += 32) {
        f32x4 a0 = *reinterpret_cast<const f32x4*>(ap + kk);
        f32x4 a1 = *reinterpret_cast<const f32x4*>(ap + kk + 4);
        bf16x8 af;
        af[0] = f2bf(a0[0]); af[1] = f2bf(a0[1]); af[2] = f2bf(a0[2]); af[3] = f2bf(a0[3]);
        af[4] = f2bf(a1[0]); af[5] = f2bf(a1[1]); af[6] = f2bf(a1[2]); af[7] = f2bf(a1[3]);
#pragma unroll
        for (int n = 0; n < 4; ++n) {
            bf16x8 bf = *reinterpret_cast<const bf16x8*>(bp + n * 16 * DIN + kk);
            acc[n] = mfma16(af, bf, acc[n]);
        }
    }
#pragma unroll
    for (int n = 0; n < 4; ++n) {
        float bv_ = bias[c0 + n * 16 + c];
#pragma unroll
        for (int r = 0; r < 4; ++r) acc[n][r] += bv_;
    }

    if (mat < 2) {
        float* dst = (mat == 0) ? q_ws : k_ws;
#pragma unroll
        for (int n = 0; n < 4; ++n)
#pragma unroll
            for (int r = 0; r < 4; ++r)
                dst[(bb * SS + 16 * wave + 4 * g + r) * HH + c0 + n * 16 + c] = acc[n][r];
    } else {
#pragma unroll
        for (int n = 0; n < 4; ++n)
#pragma unroll
            for (int r = 0; r < 4; ++r)
                vtile[n * 16 + c][16 * wave + 4 * g + r] = f2bf(acc[n][r]);
        __syncthreads();
#pragma unroll
        for (int t2 = 0; t2 < 2; ++t2) {
            int t = tid + t2 * 384;
            int d = t / 12, ch = t % 12;
            bf16x8 pk = *reinterpret_cast<const bf16x8*>(&vtile[d][ch * 8]);
            *reinterpret_cast<bf16x8*>(vt_ws + ((size_t)(bb * HH) + c0 + d) * SS + ch * 8) = pk;
        }
    }
}

// ---------------------------------------------------------------------------
// Kernel 2: row L2 norms for q,k -> qn,kn bf16. One wave per row.
// ---------------------------------------------------------------------------
__global__ __launch_bounds__(256) void norm_kernel(
    const float* __restrict__ q_ws, const float* __restrict__ k_ws,
    short* __restrict__ qn_ws, short* __restrict__ kn_ws) {
    int row = blockIdx.x * 4 + (threadIdx.x >> 6);
    int lane = threadIdx.x & 63;
    int isq = (row < 4608);
    const float* src = isq ? q_ws : k_ws;
    short* dst = isq ? qn_ws : kn_ws;
    int r = isq ? row : row - 4608;

    f32x4 v = *reinterpret_cast<const f32x4*>(src + (size_t)r * HH + lane * 4);
    float s = v[0] * v[0] + v[1] * v[1] + v[2] * v[2] + v[3] * v[3];
#pragma unroll
    for (int m = 1; m < 64; m <<= 1) s += __shfl_xor(s, m);
    float inv = 1.0f / fmaxf(sqrtf(s), 1e-8f);
    s16x4 o;
#pragma unroll
    for (int j = 0; j < 4; ++j) o[j] = f2bf(v[j] * inv);
    *reinterpret_cast<s16x4*>(dst + (size_t)r * HH + lane * 4) = o;
}

// ---------------------------------------------------------------------------
// Kernel 3: fused attn per (a,b) pair. Register-resident Sinkhorn.
// Epilogue: per-wave LDS transpose -> full-line dwordx4 stores (fixes the
// 1.8x partial-line write amplification seen in R2 counters).
// grid (48 b, 48 a), 384 thr = 6 waves; LDS 26112 B (unioned).
// ---------------------------------------------------------------------------
__global__ __launch_bounds__(384, 5) void attn_kernel(
    const short* __restrict__ qn_ws, const short* __restrict__ kn_ws,
    const float* __restrict__ q_ws, const short* __restrict__ vt_ws,
    const float* __restrict__ ln_g, const float* __restrict__ ln_b,
    float* __restrict__ out) {
    __shared__ __align__(16) char smem[26112];
    short (*Tl)[104] = (short(*)[104])smem;            // 96 x 104 bf16 = 19968 B
    float* colpart = (float*)(smem + 19968);           // [6][96] = 2304 B
    float* cinv = (float*)(smem + 22272);              // 96 f32 = 384 B
    float* etile = (float*)smem;                       // epilogue: 6 waves x 4 x 272 f32

    int b = blockIdx.x, a = blockIdx.y;
    int tid = threadIdx.x;
    int wave = tid >> 6, lane = tid & 63;
    int c = lane & 15, g = lane >> 4;

    // ---- QK^T (swapped): K[f][r] = C[i][j], i = 16*wave + c, j = 16f + 4g + r ----
    const f32x4 z4 = {0.f, 0.f, 0.f, 0.f};
    f32x4 K[6];
#pragma unroll
    for (int f = 0; f < 6; ++f) K[f] = z4;

    const short* qp = qn_ws + ((size_t)(a * SS) + 16 * wave + c) * HH + g * 8;  // B operand
    const short* kp = kn_ws + ((size_t)(b * SS) + c) * HH + g * 8;              // A operand
#pragma unroll
    for (int kk = 0; kk < HH; kk += 32) {
        bf16x8 qf = *reinterpret_cast<const bf16x8*>(qp + kk);
#pragma unroll
        for (int f = 0; f < 6; ++f) {
            bf16x8 kf = *reinterpret_cast<const bf16x8*>(kp + f * 16 * HH + kk);
            K[f] = mfma16(kf, qf, K[f]);
        }
    }

    // ---- exp(C/eps) ----
#pragma unroll
    for (int f = 0; f < 6; ++f)
#pragma unroll
        for (int r = 0; r < 4; ++r)
            K[f][r] = exp2f(K[f][r] * 14.4269504088896341f);

    // ---- Sinkhorn: 5 x (row normalize, col normalize), registers + small LDS ----
    for (int it = 0; it < 5; ++it) {
        float rs = 0.f;
#pragma unroll
        for (int f = 0; f < 6; ++f) rs += K[f][0] + K[f][1] + K[f][2] + K[f][3];
        rs += __shfl_xor(rs, 16);
        rs += __shfl_xor(rs, 32);
        float rinv = 1.0f / rs;
#pragma unroll
        for (int f = 0; f < 6; ++f)
#pragma unroll
            for (int r = 0; r < 4; ++r) K[f][r] *= rinv;

        f32x4 cs[6];
#pragma unroll
        for (int f = 0; f < 6; ++f) cs[f] = K[f];
#pragma unroll
        for (int m = 1; m < 16; m <<= 1)
#pragma unroll
            for (int f = 0; f < 6; ++f)
#pragma unroll
                for (int r = 0; r < 4; ++r) cs[f][r] += __shfl_xor(cs[f][r], m);
        if (c == 0) {
#pragma unroll
            for (int f = 0; f < 6; ++f)
                *reinterpret_cast<f32x4*>(&colpart[wave * SS + 16 * f + 4 * g]) = cs[f];
        }
        __syncthreads();
        if (tid < SS) {
            float s = colpart[0 * SS + tid] + colpart[1 * SS + tid] + colpart[2 * SS + tid] +
                      colpart[3 * SS + tid] + colpart[4 * SS + tid] + colpart[5 * SS + tid];
            cinv[tid] = 1.0f / s;
        }
        __syncthreads();
#pragma unroll
        for (int f = 0; f < 6; ++f) {
            f32x4 ci = *reinterpret_cast<const f32x4*>(&cinv[16 * f + 4 * g]);
#pragma unroll
            for (int r = 0; r < 4; ++r) K[f][r] *= ci[r];
        }
    }

    // ---- final row L2 normalize ----
    {
        float ss = 0.f;
#pragma unroll
        for (int f = 0; f < 6; ++f)
#pragma unroll
            for (int r = 0; r < 4; ++r) ss += K[f][r] * K[f][r];
        ss += __shfl_xor(ss, 16);
        ss += __shfl_xor(ss, 32);
        float linv = 1.0f / fmaxf(sqrtf(ss), 1e-12f);
#pragma unroll
        for (int f = 0; f < 6; ++f)
#pragma unroll
            for (int r = 0; r < 4; ++r) K[f][r] *= linv;
    }

    // ---- T (bf16) -> LDS ----
#pragma unroll
    for (int f = 0; f < 6; ++f) {
        s16x4 pk;
#pragma unroll
        for (int r = 0; r < 4; ++r) pk[r] = f2bf(K[f][r]);
        *reinterpret_cast<s16x4*>(&Tl[16 * wave + c][16 * f + 4 * g]) = pk;
    }
    __syncthreads();

    // ---- PV: wave w -> rows 16w..16w+15, all 256 cols ----
    f32x4 acc[16];
#pragma unroll
    for (int n = 0; n < 16; ++n) acc[n] = z4;
    const short* vp = vt_ws + ((size_t)(b * HH) + c) * SS + g * 8;
#pragma unroll
    for (int ks = 0; ks < 3; ++ks) {
        bf16x8 af = *reinterpret_cast<const bf16x8*>(&Tl[16 * wave + c][ks * 32 + g * 8]);
#pragma unroll
        for (int n = 0; n < 16; ++n) {
            bf16x8 bf = *reinterpret_cast<const bf16x8*>(vp + n * 16 * SS + ks * 32);
            acc[n] = mfma16(af, bf, acc[n]);
        }
    }

    // ---- + q residual, LN stats ----
    const float* qa = q_ws + (size_t)a * SS * HH;
    int r0 = 16 * wave + 4 * g;
    float s1[4] = {0.f, 0.f, 0.f, 0.f};
    float s2[4] = {0.f, 0.f, 0.f, 0.f};
#pragma unroll
    for (int n = 0; n < 16; ++n)
#pragma unroll
        for (int r = 0; r < 4; ++r) {
            float x = acc[n][r] + qa[(r0 + r) * HH + n * 16 + c];
            acc[n][r] = x;
            s1[r] += x;
            s2[r] += x * x;
        }
#pragma unroll
    for (int m = 1; m < 16; m <<= 1)
#pragma unroll
        for (int r = 0; r < 4; ++r) {
            s1[r] += __shfl_xor(s1[r], m);
            s2[r] += __shfl_xor(s2[r], m);
        }
    float mean[4], inv[4];
#pragma unroll
    for (int r = 0; r < 4; ++r) {
        mean[r] = s1[r] * (1.0f / 256.0f);
        float var = s2[r] * (1.0f / 256.0f) - mean[r] * mean[r];
        inv[r] = rsqrtf(var + 1e-5f);
    }

    // ---- epilogue: per-wave LDS transpose -> full-line dwordx4 stores ----
    __syncthreads();   // all waves done reading Tl before etile overwrites it
    float* wtile = etile + wave * (4 * 272);
    f32x4 g4 = *reinterpret_cast<const f32x4*>(ln_g + 4 * lane);
    f32x4 b4 = *reinterpret_cast<const f32x4*>(ln_b + 4 * lane);
    float* ob = out + ((size_t)(a * BB + b)) * SS * HH;
#pragma unroll
    for (int r = 0; r < 4; ++r) {
#pragma unroll
        for (int n = 0; n < 16; ++n)
            wtile[g * 272 + n * 16 + c] = (acc[n][r] - mean[r]) * inv[r];
        // wave-private tile: ds ordering via lgkmcnt, no barrier needed
#pragma unroll
        for (int t = 0; t < 4; ++t) {
            f32x4 x4 = *reinterpret_cast<const f32x4*>(wtile + t * 272 + 4 * lane);
            *reinterpret_cast<f32x4*>(ob + (size_t)(16 * wave + 4 * t + r) * HH + 4 * lane) =
                x4 * g4 + b4;
        }
    }
}

// ---------------------------------------------------------------------------
extern "C" void kernel_launch(void* const* d_in, const int* in_sizes, int n_in,
                              void* d_out, int out_size, void* d_ws, size_t ws_size,
                              hipStream_t stream) {
    const float* Xa = (const float*)d_in[0];
    const float* Xb = (const float*)d_in[1];
    const float* Wq = (const float*)d_in[2];
    const float* bq = (const float*)d_in[3];
    const float* Wk = (const float*)d_in[4];
    const float* bk = (const float*)d_in[5];
    const float* Wv = (const float*)d_in[6];
    const float* bv = (const float*)d_in[7];
    const float* ln_g = (const float*)d_in[8];
    const float* ln_b = (const float*)d_in[9];
    float* out = (float*)d_out;

    char* ws = (char*)d_ws;
    short* wt    = (short*)(ws);               // 1,179,648 B
    float* q_ws  = (float*)(ws + 1179648);     // 4,718,592 B
    float* k_ws  = (float*)(ws + 5898240);     // 4,718,592 B
    short* qn_ws = (short*)(ws + 10616832);    // 2,359,296 B
    short* kn_ws = (short*)(ws + 12976128);    // 2,359,296 B
    short* vt_ws = (short*)(ws + 15335424);    // 2,359,296 B (end 17,694,720)

    wt_kernel<<<dim3(2304), dim3(256), 0, stream>>>(Wq, Wk, Wv, wt);
    qkv_kernel<<<dim3(BA, 3, 4), dim3(384), 0, stream>>>(Xa, Xb, bq, bk, bv, wt,
                                                         q_ws, k_ws, vt_ws);
    norm_kernel<<<dim3(2304), dim3(256), 0, stream>>>(q_ws, k_ws, qn_ws, kn_ws);
    attn_kernel<<<dim3(BB, BA), dim3(384), 0, stream>>>(qn_ws, kn_ws, q_ws, vt_ws,
                                                        ln_g, ln_b, out);
}

// Round 4
// 306.783 us; speedup vs baseline: 1.1950x; 1.1528x over previous
//
#include <hip/hip_runtime.h>
#include <hip/hip_bf16.h>

typedef __attribute__((ext_vector_type(4))) float f32x4;
typedef __attribute__((ext_vector_type(2))) float f32x2;
typedef __attribute__((ext_vector_type(8))) short bf16x8;
typedef __attribute__((ext_vector_type(4))) short s16x4;

#define BA 48
#define BB 48
#define SS 96
#define DIN 768
#define HH 256

static __device__ __forceinline__ short f2bf(float f) {
    __hip_bfloat16 h = __float2bfloat16(f);
    return *reinterpret_cast<short*>(&h);
}

static __device__ __forceinline__ f32x4 mfma16(bf16x8 a, bf16x8 b, f32x4 c) {
    return __builtin_amdgcn_mfma_f32_16x16x32_bf16(a, b, c, 0, 0, 0);
}

// ---------------------------------------------------------------------------
// Kernel 0: convert+transpose weights: W[768][256] f32 -> Wt[3][256][768] bf16
// ---------------------------------------------------------------------------
__global__ void wt_kernel(const float* __restrict__ Wq, const float* __restrict__ Wk,
                          const float* __restrict__ Wv, short* __restrict__ wt) {
    int idx = blockIdx.x * 256 + threadIdx.x;
    if (idx >= 3 * DIN * HH) return;
    int mat = idx / (DIN * HH);
    int rem = idx - mat * DIN * HH;
    int k = rem / HH;
    int n = rem - k * HH;
    const float* W = (mat == 0) ? Wq : (mat == 1) ? Wk : Wv;
    wt[(mat * HH + n) * DIN + k] = f2bf(W[k * HH + n]);
}

// ---------------------------------------------------------------------------
// Kernel 1: QKV projection, split 2x along N.
// grid (48, 3, 2): batch, mat(0=q,1=k,2=v), 128-col tile. 384 thr = 6 waves.
// Wave w: rows 16w..16w+15 x 128 cols (acc[8] = 32 VGPR).
// ---------------------------------------------------------------------------
__global__ __launch_bounds__(384) void qkv_kernel(
    const float* __restrict__ Xa, const float* __restrict__ Xb,
    const float* __restrict__ bq, const float* __restrict__ bk, const float* __restrict__ bv,
    const short* __restrict__ wt,
    float* __restrict__ q_ws, float* __restrict__ k_ws, short* __restrict__ vt_ws) {
    __shared__ short vtile[128][104];

    int bb = blockIdx.x;
    int mat = blockIdx.y;
    int c0 = blockIdx.z * 128;
    int tid = threadIdx.x;
    int wave = tid >> 6, lane = tid & 63;
    int c = lane & 15, g = lane >> 4;

    const float* X = ((mat == 0) ? Xa : Xb) + bb * SS * DIN;
    const short* Wt = wt + mat * HH * DIN;
    const float* bias = (mat == 0) ? bq : (mat == 1) ? bk : bv;

    const f32x4 z4 = {0.f, 0.f, 0.f, 0.f};
    f32x4 acc[8];
#pragma unroll
    for (int n = 0; n < 8; ++n) acc[n] = z4;

    const float* ap = X + (16 * wave + c) * DIN + g * 8;
    const short* bp = Wt + (c0 + c) * DIN + g * 8;
    for (int kk = 0; kk < DIN; kk += 32) {
        f32x4 a0 = *reinterpret_cast<const f32x4*>(ap + kk);
        f32x4 a1 = *reinterpret_cast<const f32x4*>(ap + kk + 4);
        bf16x8 af;
        af[0] = f2bf(a0[0]); af[1] = f2bf(a0[1]); af[2] = f2bf(a0[2]); af[3] = f2bf(a0[3]);
        af[4] = f2bf(a1[0]); af[5] = f2bf(a1[1]); af[6] = f2bf(a1[2]); af[7] = f2bf(a1[3]);
#pragma unroll
        for (int n = 0; n < 8; ++n) {
            bf16x8 bf = *reinterpret_cast<const bf16x8*>(bp + n * 16 * DIN + kk);
            acc[n] = mfma16(af, bf, acc[n]);
        }
    }
#pragma unroll
    for (int n = 0; n < 8; ++n) {
        float bv_ = bias[c0 + n * 16 + c];
#pragma unroll
        for (int r = 0; r < 4; ++r) acc[n][r] += bv_;
    }

    if (mat < 2) {
        float* dst = (mat == 0) ? q_ws : k_ws;
#pragma unroll
        for (int n = 0; n < 8; ++n)
#pragma unroll
            for (int r = 0; r < 4; ++r)
                dst[(bb * SS + 16 * wave + 4 * g + r) * HH + c0 + n * 16 + c] = acc[n][r];
    } else {
#pragma unroll
        for (int n = 0; n < 8; ++n)
#pragma unroll
            for (int r = 0; r < 4; ++r)
                vtile[n * 16 + c][16 * wave + 4 * g + r] = f2bf(acc[n][r]);
        __syncthreads();
#pragma unroll
        for (int t2 = 0; t2 < 4; ++t2) {
            int t = tid + t2 * 384;
            int d = t / 12, ch = t % 12;
            bf16x8 pk = *reinterpret_cast<const bf16x8*>(&vtile[d][ch * 8]);
            *reinterpret_cast<bf16x8*>(vt_ws + ((size_t)(bb * HH) + c0 + d) * SS + ch * 8) = pk;
        }
    }
}

// ---------------------------------------------------------------------------
// Kernel 2: row L2 norms for q,k -> qn,kn bf16. One wave per row.
// ---------------------------------------------------------------------------
__global__ __launch_bounds__(256) void norm_kernel(
    const float* __restrict__ q_ws, const float* __restrict__ k_ws,
    short* __restrict__ qn_ws, short* __restrict__ kn_ws) {
    int row = blockIdx.x * 4 + (threadIdx.x >> 6);
    int lane = threadIdx.x & 63;
    int isq = (row < 4608);
    const float* src = isq ? q_ws : k_ws;
    short* dst = isq ? qn_ws : kn_ws;
    int r = isq ? row : row - 4608;

    f32x4 v = *reinterpret_cast<const f32x4*>(src + (size_t)r * HH + lane * 4);
    float s = v[0] * v[0] + v[1] * v[1] + v[2] * v[2] + v[3] * v[3];
#pragma unroll
    for (int m = 1; m < 64; m <<= 1) s += __shfl_xor(s, m);
    float inv = 1.0f / fmaxf(sqrtf(s), 1e-8f);
    s16x4 o;
#pragma unroll
    for (int j = 0; j < 4; ++j) o[j] = f2bf(v[j] * inv);
    *reinterpret_cast<s16x4*>(dst + (size_t)r * HH + lane * 4) = o;
}

// ---------------------------------------------------------------------------
// Kernel 3: fused attn per (a,b) pair, 12 waves (768 thr).
// Wave (rt = w%6, h = w/6). Waves h==0: QK^T + register Sinkhorn (rows 16rt+c).
// All waves: PV on (row-tile rt, col-half h), acc[8] = 32 VGPR -> no spill at
// the 85-VGPR cap from __launch_bounds__(768,6); 2 blocks/CU = 75% occ cap.
// ---------------------------------------------------------------------------
__global__ __launch_bounds__(768, 6) void attn_kernel(
    const short* __restrict__ qn_ws, const short* __restrict__ kn_ws,
    const float* __restrict__ q_ws, const short* __restrict__ vt_ws,
    const float* __restrict__ ln_g, const float* __restrict__ ln_b,
    float* __restrict__ out) {
    __shared__ short Tl[SS][104];          // 19968 B
    __shared__ float colpart[6][SS];       //  2304 B
    __shared__ float cinv[SS];             //   384 B
    __shared__ float stats[2][2][SS];      //  1536 B [half][s1|s2][row]
    __shared__ float etile[12][4][136];    // 26112 B per-wave transpose tiles

    int b = blockIdx.x, a = blockIdx.y;
    int tid = threadIdx.x;
    int wave = tid >> 6, lane = tid & 63;
    int rt = wave % 6, h = wave / 6;
    int c = lane & 15, g = lane >> 4;

    const f32x4 z4 = {0.f, 0.f, 0.f, 0.f};
    f32x4 K[6];

    // ---- Phase A (waves h==0): QK^T swapped; lane owns C[i=16rt+c][j=16f+4g+r] ----
    if (h == 0) {
#pragma unroll
        for (int f = 0; f < 6; ++f) K[f] = z4;
        const short* qp = qn_ws + ((size_t)(a * SS) + 16 * rt + c) * HH + g * 8;
        const short* kp = kn_ws + ((size_t)(b * SS) + c) * HH + g * 8;
#pragma unroll
        for (int kk = 0; kk < HH; kk += 32) {
            bf16x8 qf = *reinterpret_cast<const bf16x8*>(qp + kk);
#pragma unroll
            for (int f = 0; f < 6; ++f) {
                bf16x8 kf = *reinterpret_cast<const bf16x8*>(kp + f * 16 * HH + kk);
                K[f] = mfma16(kf, qf, K[f]);
            }
        }
#pragma unroll
        for (int f = 0; f < 6; ++f)
#pragma unroll
            for (int r = 0; r < 4; ++r)
                K[f][r] = exp2f(K[f][r] * 14.4269504088896341f);  // exp(10*C)
    }

    // ---- Phase B: Sinkhorn, 5 x (row norm [no barrier], col norm [2 barriers]) ----
    for (int it = 0; it < 5; ++it) {
        if (h == 0) {
            float rs = 0.f;
#pragma unroll
            for (int f = 0; f < 6; ++f) rs += K[f][0] + K[f][1] + K[f][2] + K[f][3];
            rs += __shfl_xor(rs, 16);
            rs += __shfl_xor(rs, 32);
            float rinv = 1.0f / rs;
#pragma unroll
            for (int f = 0; f < 6; ++f)
#pragma unroll
                for (int r = 0; r < 4; ++r) K[f][r] *= rinv;

            // col partials: serial per f (keeps live regs low)
#pragma unroll
            for (int f = 0; f < 6; ++f) {
                f32x4 cs = K[f];
#pragma unroll
                for (int m = 1; m < 16; m <<= 1)
#pragma unroll
                    for (int r = 0; r < 4; ++r) cs[r] += __shfl_xor(cs[r], m);
                if (c == 0)
                    *reinterpret_cast<f32x4*>(&colpart[rt][16 * f + 4 * g]) = cs;
            }
        }
        __syncthreads();
        if (tid < SS) {
            float s = colpart[0][tid] + colpart[1][tid] + colpart[2][tid] +
                      colpart[3][tid] + colpart[4][tid] + colpart[5][tid];
            cinv[tid] = 1.0f / s;
        }
        __syncthreads();
        if (h == 0) {
#pragma unroll
            for (int f = 0; f < 6; ++f) {
                f32x4 ci = *reinterpret_cast<const f32x4*>(&cinv[16 * f + 4 * g]);
#pragma unroll
                for (int r = 0; r < 4; ++r) K[f][r] *= ci[r];
            }
        }
    }

    // ---- Phase C: final row L2 normalize + T (bf16) -> LDS ----
    if (h == 0) {
        float ss = 0.f;
#pragma unroll
        for (int f = 0; f < 6; ++f)
#pragma unroll
            for (int r = 0; r < 4; ++r) ss += K[f][r] * K[f][r];
        ss += __shfl_xor(ss, 16);
        ss += __shfl_xor(ss, 32);
        float linv = 1.0f / fmaxf(sqrtf(ss), 1e-12f);
#pragma unroll
        for (int f = 0; f < 6; ++f) {
            s16x4 pk;
#pragma unroll
            for (int r = 0; r < 4; ++r) pk[r] = f2bf(K[f][r] * linv);
            *reinterpret_cast<s16x4*>(&Tl[16 * rt + c][16 * f + 4 * g]) = pk;
        }
    }
    __syncthreads();

    // ---- Phase D: PV. Wave (rt,h): rows 16rt..16rt+15, cols 128h..128h+127 ----
    f32x4 acc[8];
#pragma unroll
    for (int n = 0; n < 8; ++n) acc[n] = z4;
    const short* vp = vt_ws + ((size_t)(b * HH) + 128 * h + c) * SS + g * 8;
#pragma unroll
    for (int ks = 0; ks < 3; ++ks) {
        bf16x8 af = *reinterpret_cast<const bf16x8*>(&Tl[16 * rt + c][ks * 32 + g * 8]);
#pragma unroll
        for (int n = 0; n < 8; ++n) {
            bf16x8 bf = *reinterpret_cast<const bf16x8*>(vp + n * 16 * SS + ks * 32);
            acc[n] = mfma16(af, bf, acc[n]);
        }
    }

    // ---- Phase E: + q residual, LN stats (cross-half via LDS) ----
    const float* qa = q_ws + (size_t)a * SS * HH + 128 * h;
    int r0 = 16 * rt + 4 * g;
    float s1[4] = {0.f, 0.f, 0.f, 0.f};
    float s2[4] = {0.f, 0.f, 0.f, 0.f};
#pragma unroll
    for (int n = 0; n < 8; ++n)
#pragma unroll
        for (int r = 0; r < 4; ++r) {
            float x = acc[n][r] + qa[(r0 + r) * HH + n * 16 + c];
            acc[n][r] = x;
            s1[r] += x;
            s2[r] += x * x;
        }
#pragma unroll
    for (int m = 1; m < 16; m <<= 1)
#pragma unroll
        for (int r = 0; r < 4; ++r) {
            s1[r] += __shfl_xor(s1[r], m);
            s2[r] += __shfl_xor(s2[r], m);
        }
    if (c == 0) {
#pragma unroll
        for (int r = 0; r < 4; ++r) {
            stats[h][0][r0 + r] = s1[r];
            stats[h][1][r0 + r] = s2[r];
        }
    }
    __syncthreads();
    float mean[4], inv[4];
#pragma unroll
    for (int r = 0; r < 4; ++r) {
        float t1 = stats[0][0][r0 + r] + stats[1][0][r0 + r];
        float t2 = stats[0][1][r0 + r] + stats[1][1][r0 + r];
        mean[r] = t1 * (1.0f / 256.0f);
        float var = t2 * (1.0f / 256.0f) - mean[r] * mean[r];
        inv[r] = rsqrtf(var + 1e-5f);
    }

    // ---- Phase F: per-wave LDS transpose -> full-line f32x2 stores ----
    f32x2 g2 = *reinterpret_cast<const f32x2*>(ln_g + 128 * h + 2 * lane);
    f32x2 b2 = *reinterpret_cast<const f32x2*>(ln_b + 128 * h + 2 * lane);
    float* ob = out + ((size_t)(a * BB + b)) * SS * HH + 128 * h;
#pragma unroll
    for (int r = 0; r < 4; ++r) {
#pragma unroll
        for (int n = 0; n < 8; ++n)
            etile[wave][g][n * 16 + c] = (acc[n][r] - mean[r]) * inv[r];
        // wave-private tile: in-wave LDS ordering (lgkmcnt), no barrier needed
#pragma unroll
        for (int t = 0; t < 4; ++t) {
            f32x2 x2 = *reinterpret_cast<const f32x2*>(&etile[wave][t][2 * lane]);
            *reinterpret_cast<f32x2*>(ob + (size_t)(16 * rt + 4 * t + r) * HH + 2 * lane) =
                x2 * g2 + b2;
        }
    }
}

// ---------------------------------------------------------------------------
extern "C" void kernel_launch(void* const* d_in, const int* in_sizes, int n_in,
                              void* d_out, int out_size, void* d_ws, size_t ws_size,
                              hipStream_t stream) {
    const float* Xa = (const float*)d_in[0];
    const float* Xb = (const float*)d_in[1];
    const float* Wq = (const float*)d_in[2];
    const float* bq = (const float*)d_in[3];
    const float* Wk = (const float*)d_in[4];
    const float* bk = (const float*)d_in[5];
    const float* Wv = (const float*)d_in[6];
    const float* bv = (const float*)d_in[7];
    const float* ln_g = (const float*)d_in[8];
    const float* ln_b = (const float*)d_in[9];
    float* out = (float*)d_out;

    char* ws = (char*)d_ws;
    short* wt    = (short*)(ws);               // 1,179,648 B
    float* q_ws  = (float*)(ws + 1179648);     // 4,718,592 B
    float* k_ws  = (float*)(ws + 5898240);     // 4,718,592 B
    short* qn_ws = (short*)(ws + 10616832);    // 2,359,296 B
    short* kn_ws = (short*)(ws + 12976128);    // 2,359,296 B
    short* vt_ws = (short*)(ws + 15335424);    // 2,359,296 B (end 17,694,720)

    wt_kernel<<<dim3(2304), dim3(256), 0, stream>>>(Wq, Wk, Wv, wt);
    qkv_kernel<<<dim3(BA, 3, 2), dim3(384), 0, stream>>>(Xa, Xb, bq, bk, bv, wt,
                                                         q_ws, k_ws, vt_ws);
    norm_kernel<<<dim3(2304), dim3(256), 0, stream>>>(q_ws, k_ws, qn_ws, kn_ws);
    attn_kernel<<<dim3(BB, BA), dim3(768), 0, stream>>>(qn_ws, kn_ws, q_ws, vt_ws,
                                                        ln_g, ln_b, out);
}

// Round 5
// 306.380 us; speedup vs baseline: 1.1966x; 1.0013x over previous
//
#include <hip/hip_runtime.h>
#include <hip/hip_bf16.h>

typedef __attribute__((ext_vector_type(4))) float f32x4;
typedef __attribute__((ext_vector_type(2))) float f32x2;
typedef __attribute__((ext_vector_type(8))) short bf16x8;
typedef __attribute__((ext_vector_type(4))) short s16x4;

#define BA 48
#define BB 48
#define SS 96
#define DIN 768
#define HH 256

static __device__ __forceinline__ short f2bf(float f) {
    __hip_bfloat16 h = __float2bfloat16(f);
    return *reinterpret_cast<short*>(&h);
}

static __device__ __forceinline__ f32x4 mfma16(bf16x8 a, bf16x8 b, f32x4 c) {
    return __builtin_amdgcn_mfma_f32_16x16x32_bf16(a, b, c, 0, 0, 0);
}

// ---------------------------------------------------------------------------
// Kernel 0: convert+transpose weights: W[768][256] f32 -> Wt[3][256][768] bf16
// ---------------------------------------------------------------------------
__global__ void wt_kernel(const float* __restrict__ Wq, const float* __restrict__ Wk,
                          const float* __restrict__ Wv, short* __restrict__ wt) {
    int idx = blockIdx.x * 256 + threadIdx.x;
    if (idx >= 3 * DIN * HH) return;
    int mat = idx / (DIN * HH);
    int rem = idx - mat * DIN * HH;
    int k = rem / HH;
    int n = rem - k * HH;
    const float* W = (mat == 0) ? Wq : (mat == 1) ? Wk : Wv;
    wt[(mat * HH + n) * DIN + k] = f2bf(W[k * HH + n]);
}

// ---------------------------------------------------------------------------
// Kernel 1: QKV projection, split 2x along N.
// grid (48, 3, 2): batch, mat(0=q,1=k,2=v), 128-col tile. 384 thr = 6 waves.
// Wave w: rows 16w..16w+15 x 128 cols (acc[8] = 32 VGPR).
// ---------------------------------------------------------------------------
__global__ __launch_bounds__(384) void qkv_kernel(
    const float* __restrict__ Xa, const float* __restrict__ Xb,
    const float* __restrict__ bq, const float* __restrict__ bk, const float* __restrict__ bv,
    const short* __restrict__ wt,
    float* __restrict__ q_ws, float* __restrict__ k_ws, short* __restrict__ vt_ws) {
    __shared__ short vtile[128][104];

    int bb = blockIdx.x;
    int mat = blockIdx.y;
    int c0 = blockIdx.z * 128;
    int tid = threadIdx.x;
    int wave = tid >> 6, lane = tid & 63;
    int c = lane & 15, g = lane >> 4;

    const float* X = ((mat == 0) ? Xa : Xb) + bb * SS * DIN;
    const short* Wt = wt + mat * HH * DIN;
    const float* bias = (mat == 0) ? bq : (mat == 1) ? bk : bv;

    const f32x4 z4 = {0.f, 0.f, 0.f, 0.f};
    f32x4 acc[8];
#pragma unroll
    for (int n = 0; n < 8; ++n) acc[n] = z4;

    const float* ap = X + (16 * wave + c) * DIN + g * 8;
    const short* bp = Wt + (c0 + c) * DIN + g * 8;
    for (int kk = 0; kk < DIN; kk += 32) {
        f32x4 a0 = *reinterpret_cast<const f32x4*>(ap + kk);
        f32x4 a1 = *reinterpret_cast<const f32x4*>(ap + kk + 4);
        bf16x8 af;
        af[0] = f2bf(a0[0]); af[1] = f2bf(a0[1]); af[2] = f2bf(a0[2]); af[3] = f2bf(a0[3]);
        af[4] = f2bf(a1[0]); af[5] = f2bf(a1[1]); af[6] = f2bf(a1[2]); af[7] = f2bf(a1[3]);
#pragma unroll
        for (int n = 0; n < 8; ++n) {
            bf16x8 bf = *reinterpret_cast<const bf16x8*>(bp + n * 16 * DIN + kk);
            acc[n] = mfma16(af, bf, acc[n]);
        }
    }
#pragma unroll
    for (int n = 0; n < 8; ++n) {
        float bv_ = bias[c0 + n * 16 + c];
#pragma unroll
        for (int r = 0; r < 4; ++r) acc[n][r] += bv_;
    }

    if (mat < 2) {
        float* dst = (mat == 0) ? q_ws : k_ws;
#pragma unroll
        for (int n = 0; n < 8; ++n)
#pragma unroll
            for (int r = 0; r < 4; ++r)
                dst[(bb * SS + 16 * wave + 4 * g + r) * HH + c0 + n * 16 + c] = acc[n][r];
    } else {
#pragma unroll
        for (int n = 0; n < 8; ++n)
#pragma unroll
            for (int r = 0; r < 4; ++r)
                vtile[n * 16 + c][16 * wave + 4 * g + r] = f2bf(acc[n][r]);
        __syncthreads();
#pragma unroll
        for (int t2 = 0; t2 < 4; ++t2) {
            int t = tid + t2 * 384;
            int d = t / 12, ch = t % 12;
            bf16x8 pk = *reinterpret_cast<const bf16x8*>(&vtile[d][ch * 8]);
            *reinterpret_cast<bf16x8*>(vt_ws + ((size_t)(bb * HH) + c0 + d) * SS + ch * 8) = pk;
        }
    }
}

// ---------------------------------------------------------------------------
// Kernel 2: row L2 norms for q,k -> qn,kn bf16. One wave per row.
// ---------------------------------------------------------------------------
__global__ __launch_bounds__(256) void norm_kernel(
    const float* __restrict__ q_ws, const float* __restrict__ k_ws,
    short* __restrict__ qn_ws, short* __restrict__ kn_ws) {
    int row = blockIdx.x * 4 + (threadIdx.x >> 6);
    int lane = threadIdx.x & 63;
    int isq = (row < 4608);
    const float* src = isq ? q_ws : k_ws;
    short* dst = isq ? qn_ws : kn_ws;
    int r = isq ? row : row - 4608;

    f32x4 v = *reinterpret_cast<const f32x4*>(src + (size_t)r * HH + lane * 4);
    float s = v[0] * v[0] + v[1] * v[1] + v[2] * v[2] + v[3] * v[3];
#pragma unroll
    for (int m = 1; m < 64; m <<= 1) s += __shfl_xor(s, m);
    float inv = 1.0f / fmaxf(sqrtf(s), 1e-8f);
    s16x4 o;
#pragma unroll
    for (int j = 0; j < 4; ++j) o[j] = f2bf(v[j] * inv);
    *reinterpret_cast<s16x4*>(dst + (size_t)r * HH + lane * 4) = o;
}

// ---------------------------------------------------------------------------
// Kernel 3: fused attn per (a,b) pair, 12 waves (768 thr).
// Wave (rt = w%6, h = w/6). Waves h==0: QK^T + register Sinkhorn (rows 16rt+c).
// All waves: PV on (row-tile rt, col-half h), acc[8] = 32 VGPR -> no spill at
// the 85-VGPR cap from __launch_bounds__(768,6); 2 blocks/CU = 75% occ cap.
// ---------------------------------------------------------------------------
__global__ __launch_bounds__(768, 6) void attn_kernel(
    const short* __restrict__ qn_ws, const short* __restrict__ kn_ws,
    const float* __restrict__ q_ws, const short* __restrict__ vt_ws,
    const float* __restrict__ ln_g, const float* __restrict__ ln_b,
    float* __restrict__ out) {
    __shared__ short Tl[SS][104];          // 19968 B
    __shared__ float colpart[6][SS];       //  2304 B
    __shared__ float cinv[SS];             //   384 B
    __shared__ float stats[2][2][SS];      //  1536 B [half][s1|s2][row]
    __shared__ float etile[12][4][136];    // 26112 B per-wave transpose tiles

    int b = blockIdx.x, a = blockIdx.y;
    int tid = threadIdx.x;
    int wave = tid >> 6, lane = tid & 63;
    int rt = wave % 6, h = wave / 6;
    int c = lane & 15, g = lane >> 4;

    const f32x4 z4 = {0.f, 0.f, 0.f, 0.f};
    f32x4 K[6];

    // ---- Phase A (waves h==0): QK^T swapped; lane owns C[i=16rt+c][j=16f+4g+r] ----
    if (h == 0) {
#pragma unroll
        for (int f = 0; f < 6; ++f) K[f] = z4;
        const short* qp = qn_ws + ((size_t)(a * SS) + 16 * rt + c) * HH + g * 8;
        const short* kp = kn_ws + ((size_t)(b * SS) + c) * HH + g * 8;
#pragma unroll
        for (int kk = 0; kk < HH; kk += 32) {
            bf16x8 qf = *reinterpret_cast<const bf16x8*>(qp + kk);
#pragma unroll
            for (int f = 0; f < 6; ++f) {
                bf16x8 kf = *reinterpret_cast<const bf16x8*>(kp + f * 16 * HH + kk);
                K[f] = mfma16(kf, qf, K[f]);
            }
        }
#pragma unroll
        for (int f = 0; f < 6; ++f)
#pragma unroll
            for (int r = 0; r < 4; ++r)
                K[f][r] = exp2f(K[f][r] * 14.4269504088896341f);  // exp(10*C)
    }

    // ---- Phase B: Sinkhorn, 5 x (row norm [no barrier], col norm [2 barriers]) ----
    for (int it = 0; it < 5; ++it) {
        if (h == 0) {
            float rs = 0.f;
#pragma unroll
            for (int f = 0; f < 6; ++f) rs += K[f][0] + K[f][1] + K[f][2] + K[f][3];
            rs += __shfl_xor(rs, 16);
            rs += __shfl_xor(rs, 32);
            float rinv = 1.0f / rs;
#pragma unroll
            for (int f = 0; f < 6; ++f)
#pragma unroll
                for (int r = 0; r < 4; ++r) K[f][r] *= rinv;

            // col partials: serial per f (keeps live regs low)
#pragma unroll
            for (int f = 0; f < 6; ++f) {
                f32x4 cs = K[f];
#pragma unroll
                for (int m = 1; m < 16; m <<= 1)
#pragma unroll
                    for (int r = 0; r < 4; ++r) cs[r] += __shfl_xor(cs[r], m);
                if (c == 0)
                    *reinterpret_cast<f32x4*>(&colpart[rt][16 * f + 4 * g]) = cs;
            }
        }
        __syncthreads();
        if (tid < SS) {
            float s = colpart[0][tid] + colpart[1][tid] + colpart[2][tid] +
                      colpart[3][tid] + colpart[4][tid] + colpart[5][tid];
            cinv[tid] = 1.0f / s;
        }
        __syncthreads();
        if (h == 0) {
#pragma unroll
            for (int f = 0; f < 6; ++f) {
                f32x4 ci = *reinterpret_cast<const f32x4*>(&cinv[16 * f + 4 * g]);
#pragma unroll
                for (int r = 0; r < 4; ++r) K[f][r] *= ci[r];
            }
        }
    }

    // ---- Phase C: final row L2 normalize + T (bf16) -> LDS ----
    if (h == 0) {
        float ss = 0.f;
#pragma unroll
        for (int f = 0; f < 6; ++f)
#pragma unroll
            for (int r = 0; r < 4; ++r) ss += K[f][r] * K[f][r];
        ss += __shfl_xor(ss, 16);
        ss += __shfl_xor(ss, 32);
        float linv = 1.0f / fmaxf(sqrtf(ss), 1e-12f);
#pragma unroll
        for (int f = 0; f < 6; ++f) {
            s16x4 pk;
#pragma unroll
            for (int r = 0; r < 4; ++r) pk[r] = f2bf(K[f][r] * linv);
            *reinterpret_cast<s16x4*>(&Tl[16 * rt + c][16 * f + 4 * g]) = pk;
        }
    }
    __syncthreads();

    // ---- Phase D: PV. Wave (rt,h): rows 16rt..16rt+15, cols 128h..128h+127 ----
    f32x4 acc[8];
#pragma unroll
    for (int n = 0; n < 8; ++n) acc[n] = z4;
    const short* vp = vt_ws + ((size_t)(b * HH) + 128 * h + c) * SS + g * 8;
#pragma unroll
    for (int ks = 0; ks < 3; ++ks) {
        bf16x8 af = *reinterpret_cast<const bf16x8*>(&Tl[16 * rt + c][ks * 32 + g * 8]);
#pragma unroll
        for (int n = 0; n < 8; ++n) {
            bf16x8 bf = *reinterpret_cast<const bf16x8*>(vp + n * 16 * SS + ks * 32);
            acc[n] = mfma16(af, bf, acc[n]);
        }
    }

    // ---- Phase E: + q residual, LN stats (cross-half via LDS) ----
    const float* qa = q_ws + (size_t)a * SS * HH + 128 * h;
    int r0 = 16 * rt + 4 * g;
    float s1[4] = {0.f, 0.f, 0.f, 0.f};
    float s2[4] = {0.f, 0.f, 0.f, 0.f};
#pragma unroll
    for (int n = 0; n < 8; ++n)
#pragma unroll
        for (int r = 0; r < 4; ++r) {
            float x = acc[n][r] + qa[(r0 + r) * HH + n * 16 + c];
            acc[n][r] = x;
            s1[r] += x;
            s2[r] += x * x;
        }
#pragma unroll
    for (int m = 1; m < 16; m <<= 1)
#pragma unroll
        for (int r = 0; r < 4; ++r) {
            s1[r] += __shfl_xor(s1[r], m);
            s2[r] += __shfl_xor(s2[r], m);
        }
    if (c == 0) {
#pragma unroll
        for (int r = 0; r < 4; ++r) {
            stats[h][0][r0 + r] = s1[r];
            stats[h][1][r0 + r] = s2[r];
        }
    }
    __syncthreads();
    float mean[4], inv[4];
#pragma unroll
    for (int r = 0; r < 4; ++r) {
        float t1 = stats[0][0][r0 + r] + stats[1][0][r0 + r];
        float t2 = stats[0][1][r0 + r] + stats[1][1][r0 + r];
        mean[r] = t1 * (1.0f / 256.0f);
        float var = t2 * (1.0f / 256.0f) - mean[r] * mean[r];
        inv[r] = rsqrtf(var + 1e-5f);
    }

    // ---- Phase F: per-wave LDS transpose -> full-line f32x2 stores ----
    f32x2 g2 = *reinterpret_cast<const f32x2*>(ln_g + 128 * h + 2 * lane);
    f32x2 b2 = *reinterpret_cast<const f32x2*>(ln_b + 128 * h + 2 * lane);
    float* ob = out + ((size_t)(a * BB + b)) * SS * HH + 128 * h;
#pragma unroll
    for (int r = 0; r < 4; ++r) {
#pragma unroll
        for (int n = 0; n < 8; ++n)
            etile[wave][g][n * 16 + c] = (acc[n][r] - mean[r]) * inv[r];
        // wave-private tile: in-wave LDS ordering (lgkmcnt), no barrier needed
#pragma unroll
        for (int t = 0; t < 4; ++t) {
            f32x2 x2 = *reinterpret_cast<const f32x2*>(&etile[wave][t][2 * lane]);
            *reinterpret_cast<f32x2*>(ob + (size_t)(16 * rt + 4 * t + r) * HH + 2 * lane) =
                x2 * g2 + b2;
        }
    }
}

// ---------------------------------------------------------------------------
extern "C" void kernel_launch(void* const* d_in, const int* in_sizes, int n_in,
                              void* d_out, int out_size, void* d_ws, size_t ws_size,
                              hipStream_t stream) {
    const float* Xa = (const float*)d_in[0];
    const float* Xb = (const float*)d_in[1];
    const float* Wq = (const float*)d_in[2];
    const float* bq = (const float*)d_in[3];
    const float* Wk = (const float*)d_in[4];
    const float* bk = (const float*)d_in[5];
    const float* Wv = (const float*)d_in[6];
    const float* bv = (const float*)d_in[7];
    const float* ln_g = (const float*)d_in[8];
    const float* ln_b = (const float*)d_in[9];
    float* out = (float*)d_out;

    char* ws = (char*)d_ws;
    short* wt    = (short*)(ws);               // 1,179,648 B
    float* q_ws  = (float*)(ws + 1179648);     // 4,718,592 B
    float* k_ws  = (float*)(ws + 5898240);     // 4,718,592 B
    short* qn_ws = (short*)(ws + 10616832);    // 2,359,296 B
    short* kn_ws = (short*)(ws + 12976128);    // 2,359,296 B
    short* vt_ws = (short*)(ws + 15335424);    // 2,359,296 B (end 17,694,720)

    wt_kernel<<<dim3(2304), dim3(256), 0, stream>>>(Wq, Wk, Wv, wt);
    qkv_kernel<<<dim3(BA, 3, 2), dim3(384), 0, stream>>>(Xa, Xb, bq, bk, bv, wt,
                                                         q_ws, k_ws, vt_ws);
    norm_kernel<<<dim3(2304), dim3(256), 0, stream>>>(q_ws, k_ws, qn_ws, kn_ws);
    attn_kernel<<<dim3(BB, BA), dim3(768), 0, stream>>>(qn_ws, kn_ws, q_ws, vt_ws,
                                                        ln_g, ln_b, out);
}